// Round 12
// baseline (253.753 us; speedup 1.0000x reference)
//
#include <hip/hip_runtime.h>
#include <math.h>

#define NN 100000
#define NE 1600000
#define EE 1700000       // NE + NN self loops
#define HD 128
#define NH (NN*HD)

#define BSH 8            // bucket = dst >> 8  (256 nodes per bucket)
#define NBUK 391         // ceil(NN / 256)
#define CAP 6144         // per-bucket staging capacity (mean 4352, sigma ~66)
#define EPB 4096         // edges per partition block
#define P1B ((EE + EPB - 1) / EPB)   // 416
#define GEMMB 1563       // gemm blocks (64 rows each)

typedef _Float16 f16x8 __attribute__((ext_vector_type(8)));
typedef float    f32x4 __attribute__((ext_vector_type(4)));

__device__ __forceinline__ float fast_tanh(float x) {
    float e = __expf(2.f * x);
    return 1.f - 2.f * __builtin_amdgcn_rcpf(e + 1.f);
}

// ================= FUSED: GEMM(+scores, inline W-transpose) ∥ CSR bucket partition ===========
__launch_bounds__(256) __global__
void gemm_part_kernel(const float* __restrict__ A, const float* __restrict__ W,
                      _Float16* __restrict__ H, const float* __restrict__ a_src,
                      const float* __restrict__ a_dst, float* __restrict__ s_src,
                      float* __restrict__ s_dst,
                      const int* __restrict__ ei, int* __restrict__ bucketCount,
                      unsigned* __restrict__ stage) {
    __shared__ __align__(16) char smem[HD*HD*2 + HD*8];    // 33 KB union
    int bid = blockIdx.x;
    int t = threadIdx.x;

    if (bid < GEMMB) {
        // ---------------- GEMM body ----------------
        _Float16* Wl = (_Float16*)smem;                    // 32 KB: Wl[n][k], slot-swizzled
        float* asl = (float*)(smem + HD*HD*2);
        float* adl = asl + HD;
        // load W fp32 [k][n] (4096 float4s), convert + transpose + swizzle into LDS
        #pragma unroll
        for (int i = 0; i < 16; ++i) {
            int f = t + 256*i;                 // float4 index over 4096
            int k = f >> 5;                    // row (k) 0..127
            int n4 = f & 31;                   // float4 within row
            float4 wv = ((const float4*)W)[f];
            int slot = k >> 3, ke = k & 7;
            int n0 = n4*4;
            Wl[(size_t)((n0+0)*16 + (slot ^ ((n0+0) & 7)))*8 + ke] = (_Float16)wv.x;
            Wl[(size_t)((n0+1)*16 + (slot ^ ((n0+1) & 7)))*8 + ke] = (_Float16)wv.y;
            Wl[(size_t)((n0+2)*16 + (slot ^ ((n0+2) & 7)))*8 + ke] = (_Float16)wv.z;
            Wl[(size_t)((n0+3)*16 + (slot ^ ((n0+3) & 7)))*8 + ke] = (_Float16)wv.w;
        }
        if (t < HD) { asl[t] = a_src[t]; adl[t] = a_dst[t]; }
        __syncthreads();

        int wave = t >> 6, lane = t & 63;
        int row0 = bid*64 + wave*16;
        int h8   = lane >> 4;
        int col  = lane & 15;
        int arow = row0 + col; if (arow >= NN) arow = NN - 1;
        const float* Af = A + (size_t)arow*HD + h8*8;

        f32x4 acc[8];
        #pragma unroll
        for (int i = 0; i < 8; ++i) acc[i] = (f32x4){0.f,0.f,0.f,0.f};

        #pragma unroll
        for (int step = 0; step < 4; ++step) {
            float4 fa = *(const float4*)(Af + step*32);
            float4 fb = *(const float4*)(Af + step*32 + 4);
            f16x8 a = { (_Float16)fa.x, (_Float16)fa.y, (_Float16)fa.z, (_Float16)fa.w,
                        (_Float16)fb.x, (_Float16)fb.y, (_Float16)fb.z, (_Float16)fb.w };
            #pragma unroll
            for (int nt = 0; nt < 8; ++nt) {
                int n = nt*16 + col;
                int slot = step*4 + h8;
                f16x8 bfr = *(const f16x8*)(Wl + (size_t)(n*16 + (slot ^ (n & 7)))*8);
                acc[nt] = __builtin_amdgcn_mfma_f32_16x16x32_f16(a, bfr, acc[nt], 0, 0, 0);
            }
        }

        int orow0 = row0 + h8*4;               // D: col=lane&15, row=(lane>>4)*4+reg
        #pragma unroll
        for (int nt = 0; nt < 8; ++nt) {
            int c = nt*16 + col;
            #pragma unroll
            for (int r = 0; r < 4; ++r) {
                int row = orow0 + r;
                if (row < NN) H[(size_t)row*HD + c] = (_Float16)acc[nt][r];
            }
        }

        float pS[4] = {0.f,0.f,0.f,0.f}, pD[4] = {0.f,0.f,0.f,0.f};
        #pragma unroll
        for (int nt = 0; nt < 8; ++nt) {
            float as_ = asl[nt*16 + col], ad_ = adl[nt*16 + col];
            #pragma unroll
            for (int r = 0; r < 4; ++r) { pS[r] += acc[nt][r]*as_; pD[r] += acc[nt][r]*ad_; }
        }
        #pragma unroll
        for (int off = 1; off < 16; off <<= 1) {
            #pragma unroll
            for (int r = 0; r < 4; ++r) {
                pS[r] += __shfl_xor(pS[r], off);
                pD[r] += __shfl_xor(pD[r], off);
            }
        }
        if (col == 0) {
            #pragma unroll
            for (int r = 0; r < 4; ++r) {
                int row = orow0 + r;
                if (row < NN) { s_src[row] = pS[r]; s_dst[row] = pD[r]; }
            }
        }
    } else if (ei) {
        // ---------------- partition body ----------------
        int* hist = (int*)smem;
        int* base = hist + NBUK;
        for (int i = t; i < NBUK; i += 256) hist[i] = 0;
        __syncthreads();
        int pb = bid - GEMMB;
        int e0 = pb * EPB;
        int e1 = min(e0 + EPB, EE);
        for (int e = e0 + t; e < e1; e += 256) {
            int d = (e < NE) ? ei[NE + e] : e - NE;
            atomicAdd(&hist[d >> BSH], 1);
        }
        __syncthreads();
        for (int i = t; i < NBUK; i += 256) {
            base[i] = atomicAdd(&bucketCount[i], hist[i]);
            hist[i] = 0;                       // reuse as cursor
        }
        __syncthreads();
        for (int e = e0 + t; e < e1; e += 256) {
            int s, d;
            if (e < NE) { s = ei[e]; d = ei[NE + e]; } else { s = e - NE; d = s; }
            int b = d >> BSH;
            int pos = base[b] + atomicAdd(&hist[b], 1);
            if (pos < CAP)
                stage[(size_t)b * CAP + pos] = (unsigned)s | ((unsigned)(d & 255) << 20);
        }
    }
}

// ================= bucket build: inline prefix + deg/scan/scatter =================
__launch_bounds__(256) __global__
void bucket_build_kernel(const unsigned* __restrict__ stage, const int* __restrict__ bucketCount,
                         int* __restrict__ row_ptr, int* __restrict__ csr_src) {
    int b = blockIdx.x;
    int t = threadIdx.x;
    __shared__ int ldeg[256];
    __shared__ int loff[256];
    __shared__ int sbase;
    // inline exclusive prefix of bucketCount[0..b)
    int c = 0;
    if (t < b) c = bucketCount[t];
    if (t + 256 < b) c += bucketCount[t + 256];
    loff[t] = c;
    ldeg[t] = 0;
    __syncthreads();
    for (int off = 128; off >= 1; off >>= 1) {
        if (t < off) loff[t] += loff[t + off];
        __syncthreads();
    }
    if (t == 0) sbase = loff[0];
    __syncthreads();
    int cnt  = bucketCount[b];
    int base = sbase;
    const unsigned* sp = stage + (size_t)b * CAP;
    for (int i = t; i < cnt; i += 256) atomicAdd(&ldeg[sp[i] >> 20], 1);
    __syncthreads();
    int v = ldeg[t];
    loff[t] = v;
    __syncthreads();
    for (int off = 1; off < 256; off <<= 1) {
        int tmp = (t >= off) ? loff[t - off] : 0;
        __syncthreads();
        loff[t] += tmp;
        __syncthreads();
    }
    int excl = loff[t] - v;
    int n = (b << BSH) + t;
    if (n < NN) row_ptr[n] = base + excl;
    if (b == NBUK - 1 && t == 0) row_ptr[NN] = EE;
    ldeg[t] = excl;                        // reuse as cursor
    __syncthreads();
    for (int i = t; i < cnt; i += 256) {
        unsigned p = sp[i];
        int lp = atomicAdd(&ldeg[p >> 20], 1);
        csr_src[base + lp] = (int)(p & 0xFFFFFu);
    }
}

// ================= fused per-node softmax + gather-aggregate =================
// 4 nodes/wave (natural order); 8 edges/batch, all 16 gathers issued before compute.
// Tail slots clamp to last edge (L1-hit re-read) with w=0.
template<int LAYER>
__launch_bounds__(256) __global__
void gat_node_kernel(const int* __restrict__ row_ptr, const int* __restrict__ csr_src,
                     const float* __restrict__ s_src, const float* __restrict__ s_dst,
                     const _Float16* __restrict__ Hh, const float* __restrict__ bias,
                     float* __restrict__ out) {
    int wid = (blockIdx.x * blockDim.x + threadIdx.x) >> 6;
    int lane = threadIdx.x & 63;
    int g = lane >> 4, l16 = lane & 15;
    int n = wid*4 + g;                     // NN divisible by 4: no partial waves
    if (n >= NN) return;
    int r0 = row_ptr[n], r1 = row_ptr[n+1];
    int last = r1 - 1;
    float sdv = s_dst[n];

    float denom = 0.f;
    float acc[8] = {0.f,0.f,0.f,0.f,0.f,0.f,0.f,0.f};

    for (int j = r0; j < r1; j += 8) {
        int ss0, ss1, ss2, ss3, ss4, ss5, ss6, ss7;
        ss0 = csr_src[j];
        ss1 = csr_src[j+1 <= last ? j+1 : last];
        ss2 = csr_src[j+2 <= last ? j+2 : last];
        ss3 = csr_src[j+3 <= last ? j+3 : last];
        ss4 = csr_src[j+4 <= last ? j+4 : last];
        ss5 = csr_src[j+5 <= last ? j+5 : last];
        ss6 = csr_src[j+6 <= last ? j+6 : last];
        ss7 = csr_src[j+7 <= last ? j+7 : last];
        // issue all 16 gathers before dependent compute
        f16x8 h0 = *(const f16x8*)(Hh + (unsigned)(ss0 << 7) + l16*8);
        f16x8 h1 = *(const f16x8*)(Hh + (unsigned)(ss1 << 7) + l16*8);
        f16x8 h2 = *(const f16x8*)(Hh + (unsigned)(ss2 << 7) + l16*8);
        f16x8 h3 = *(const f16x8*)(Hh + (unsigned)(ss3 << 7) + l16*8);
        f16x8 h4 = *(const f16x8*)(Hh + (unsigned)(ss4 << 7) + l16*8);
        f16x8 h5 = *(const f16x8*)(Hh + (unsigned)(ss5 << 7) + l16*8);
        f16x8 h6 = *(const f16x8*)(Hh + (unsigned)(ss6 << 7) + l16*8);
        f16x8 h7 = *(const f16x8*)(Hh + (unsigned)(ss7 << 7) + l16*8);
        float v0 = s_src[ss0], v1 = s_src[ss1], v2 = s_src[ss2], v3 = s_src[ss3];
        float v4 = s_src[ss4], v5 = s_src[ss5], v6 = s_src[ss6], v7 = s_src[ss7];

        float e0 = v0 + sdv, e1 = v1 + sdv, e2 = v2 + sdv, e3 = v3 + sdv;
        float e4 = v4 + sdv, e5 = v5 + sdv, e6 = v6 + sdv, e7 = v7 + sdv;
        e0 = e0 > 0.f ? e0 : 0.2f*e0;  e1 = e1 > 0.f ? e1 : 0.2f*e1;
        e2 = e2 > 0.f ? e2 : 0.2f*e2;  e3 = e3 > 0.f ? e3 : 0.2f*e3;
        e4 = e4 > 0.f ? e4 : 0.2f*e4;  e5 = e5 > 0.f ? e5 : 0.2f*e5;
        e6 = e6 > 0.f ? e6 : 0.2f*e6;  e7 = e7 > 0.f ? e7 : 0.2f*e7;
        float w0 = __expf(fminf(e0, 80.f));
        float w1 = (j+1 < r1) ? __expf(fminf(e1, 80.f)) : 0.f;
        float w2 = (j+2 < r1) ? __expf(fminf(e2, 80.f)) : 0.f;
        float w3 = (j+3 < r1) ? __expf(fminf(e3, 80.f)) : 0.f;
        float w4 = (j+4 < r1) ? __expf(fminf(e4, 80.f)) : 0.f;
        float w5 = (j+5 < r1) ? __expf(fminf(e5, 80.f)) : 0.f;
        float w6 = (j+6 < r1) ? __expf(fminf(e6, 80.f)) : 0.f;
        float w7 = (j+7 < r1) ? __expf(fminf(e7, 80.f)) : 0.f;
        denom += ((w0 + w1) + (w2 + w3)) + ((w4 + w5) + (w6 + w7));
        #pragma unroll
        for (int i = 0; i < 8; ++i) {
            float a01 = w0*(float)h0[i] + w1*(float)h1[i];
            float a23 = w2*(float)h2[i] + w3*(float)h3[i];
            float a45 = w4*(float)h4[i] + w5*(float)h5[i];
            float a67 = w6*(float)h6[i] + w7*(float)h7[i];
            acc[i] += (a01 + a23) + (a45 + a67);
        }
    }

    float inv = __builtin_amdgcn_rcpf(denom);
    float* op = out + (unsigned)(n << 7) + l16*8;
    float4 b0 = *(const float4*)(bias + l16*8);
    float4 b1 = *(const float4*)(bias + l16*8 + 4);
    float r[8];
    r[0]=acc[0]*inv+b0.x; r[1]=acc[1]*inv+b0.y; r[2]=acc[2]*inv+b0.z; r[3]=acc[3]*inv+b0.w;
    r[4]=acc[4]*inv+b1.x; r[5]=acc[5]*inv+b1.y; r[6]=acc[6]*inv+b1.z; r[7]=acc[7]*inv+b1.w;
    if (LAYER == 1) {
        #pragma unroll
        for (int i = 0; i < 8; ++i) r[i] = fast_tanh(r[i]);
    } else {
        float4 x0 = *(const float4*)op;
        float4 x1 = *(const float4*)(op + 4);
        r[0]=fmaxf(x0.x,r[0]); r[1]=fmaxf(x0.y,r[1]); r[2]=fmaxf(x0.z,r[2]); r[3]=fmaxf(x0.w,r[3]);
        r[4]=fmaxf(x1.x,r[4]); r[5]=fmaxf(x1.y,r[5]); r[6]=fmaxf(x1.z,r[6]); r[7]=fmaxf(x1.w,r[7]);
    }
    *(float4*)op       = make_float4(r[0],r[1],r[2],r[3]);
    *(float4*)(op + 4) = make_float4(r[4],r[5],r[6],r[7]);
}

extern "C" void kernel_launch(void* const* d_in, const int* in_sizes, int n_in,
                              void* d_out, int out_size, void* d_ws, size_t ws_size,
                              hipStream_t stream) {
    const float* x   = (const float*)d_in[0];
    const int*   ei  = (const int*)d_in[1];
    // d_in[2] = edge_weight, unused by GATConv(edge_dim=None)
    const float* W1  = (const float*)d_in[3];
    const float* as1 = (const float*)d_in[4];
    const float* ad1 = (const float*)d_in[5];
    const float* b1  = (const float*)d_in[6];
    const float* W2  = (const float*)d_in[7];
    const float* as2 = (const float*)d_in[8];
    const float* ad2 = (const float*)d_in[9];
    const float* b2  = (const float*)d_in[10];
    float* out = (float*)d_out;

    char* wsb = (char*)d_ws;
    _Float16* h   = (_Float16*)wsb;                  // NH halves (25.6 MB)
    float* ssrc   = (float*)(h + NH);                // NN
    float* sdst   = ssrc + NN;                       // NN
    int* row_ptr  = (int*)(sdst + NN);               // NN+2
    int* csr_src  = row_ptr + NN + 2;                // EE
    int* bucketCount = csr_src + EE;                 // NBUK (zeroed every launch)
    unsigned* stage  = (unsigned*)(bucketCount + NBUK + 1);  // NBUK*CAP (9.6 MB)

    dim3 B(256);
    int node_blocks = NN / 16;                       // 6250 (4 nodes/wave, 4 waves/block)

    // ===== prep (zero bucket counters every launch; graph-replay safe) =====
    hipMemsetAsync(bucketCount, 0, (NBUK + 1) * sizeof(int), stream);

    // ===== layer-1 GEMM ∥ CSR partition (independent work, one dispatch) =====
    gemm_part_kernel<<<GEMMB + P1B, B, 0, stream>>>(x, W1, h, as1, ad1, ssrc, sdst,
                                                    ei, bucketCount, stage);
    bucket_build_kernel<<<NBUK, B, 0, stream>>>(stage, bucketCount, row_ptr, csr_src);

    // ===== layer 1 aggregate =====
    gat_node_kernel<1><<<node_blocks, B, 0, stream>>>(row_ptr, csr_src, ssrc, sdst, h, b1, out);

    // ===== layer 2 (x1 fp32 lives in d_out; max fused into epilogue) =====
    gemm_part_kernel<<<GEMMB, B, 0, stream>>>(out, W2, h, as2, ad2, ssrc, sdst,
                                              nullptr, nullptr, nullptr);
    gat_node_kernel<2><<<node_blocks, B, 0, stream>>>(row_ptr, csr_src, ssrc, sdst, h, b2, out);
}

// Round 13
// 225.502 us; speedup vs baseline: 1.1253x; 1.1253x over previous
//
#include <hip/hip_runtime.h>
#include <math.h>

#define NN 100000
#define NE 1600000
#define EE 1700000       // NE + NN self loops
#define HD 128
#define NH (NN*HD)

#define BSH 8            // bucket = dst >> 8  (256 nodes per bucket)
#define NBUK 391         // ceil(NN / 256)
#define CAP 6144         // per-bucket staging capacity (mean 4352, sigma ~66)
#define EPB 8192         // edges per partition block
#define P1B ((EE + EPB - 1) / EPB)   // 208
#define GEMMB 1563       // gemm blocks (64 rows each)

typedef _Float16 f16x8 __attribute__((ext_vector_type(8)));
typedef float    f32x4 __attribute__((ext_vector_type(4)));

__device__ __forceinline__ float fast_tanh(float x) {
    float e = __expf(2.f * x);
    return 1.f - 2.f * __builtin_amdgcn_rcpf(e + 1.f);
}

// ====== prep: W (fp32 [k][n]) -> Wt (fp16 [n][k]) for both layers + zero bucketCount ======
__global__ void prep_kernel(const float* __restrict__ W1, const float* __restrict__ W2,
                            _Float16* __restrict__ Wt1, _Float16* __restrict__ Wt2,
                            int* __restrict__ bucketCount) {
    int b = blockIdx.x;
    int t = threadIdx.x;
    if (b < 128) {
        const float* W = (b < 64) ? W1 : W2;
        _Float16* Wt   = (b < 64) ? Wt1 : Wt2;
        int e = (b & 63) * 256 + t;
        int k = e >> 7, n = e & 127;
        Wt[n*HD + k] = (_Float16)W[e];
    } else {
        for (int i = t; i < NBUK; i += 256) bucketCount[i] = 0;
    }
}

// ================= FUSED: GEMM(+scores) layer blocks ∥ CSR bucket partition =================
__launch_bounds__(256) __global__
void gemm_part_kernel(const float* __restrict__ A, const _Float16* __restrict__ Wt,
                      _Float16* __restrict__ H, const float* __restrict__ a_src,
                      const float* __restrict__ a_dst, float* __restrict__ s_src,
                      float* __restrict__ s_dst,
                      const int* __restrict__ ei, int* __restrict__ bucketCount,
                      unsigned* __restrict__ stage) {
    __shared__ __align__(16) char smem[HD*HD*2 + HD*8];    // 33 KB union
    int bid = blockIdx.x;
    int t = threadIdx.x;

    if (bid < GEMMB) {
        // ---------------- GEMM body ----------------
        _Float16* Wl = (_Float16*)smem;                    // 32 KB, slot-swizzled
        float* asl = (float*)(smem + HD*HD*2);
        float* adl = asl + HD;
        #pragma unroll
        for (int i = 0; i < 8; ++i) {
            int f = t + 256*i;                 // float4 index over 2048
            int n = f >> 4, slot = f & 15;     // slot = 16B chunk of 8 fp16 along k
            int phys = n*16 + (slot ^ (n & 7));
            *(float4*)(Wl + (size_t)phys*8) = ((const float4*)Wt)[f];
        }
        if (t < HD) { asl[t] = a_src[t]; adl[t] = a_dst[t]; }
        __syncthreads();

        int wave = t >> 6, lane = t & 63;
        int row0 = bid*64 + wave*16;
        int h8   = lane >> 4;
        int col  = lane & 15;
        int arow = row0 + col; if (arow >= NN) arow = NN - 1;
        const float* Af = A + (size_t)arow*HD + h8*8;

        f32x4 acc[8];
        #pragma unroll
        for (int i = 0; i < 8; ++i) acc[i] = (f32x4){0.f,0.f,0.f,0.f};

        #pragma unroll
        for (int step = 0; step < 4; ++step) {
            float4 fa = *(const float4*)(Af + step*32);
            float4 fb = *(const float4*)(Af + step*32 + 4);
            f16x8 a = { (_Float16)fa.x, (_Float16)fa.y, (_Float16)fa.z, (_Float16)fa.w,
                        (_Float16)fb.x, (_Float16)fb.y, (_Float16)fb.z, (_Float16)fb.w };
            #pragma unroll
            for (int nt = 0; nt < 8; ++nt) {
                int n = nt*16 + col;
                int slot = step*4 + h8;
                f16x8 bfr = *(const f16x8*)(Wl + (size_t)(n*16 + (slot ^ (n & 7)))*8);
                acc[nt] = __builtin_amdgcn_mfma_f32_16x16x32_f16(a, bfr, acc[nt], 0, 0, 0);
            }
        }

        int orow0 = row0 + h8*4;               // D: col=lane&15, row=(lane>>4)*4+reg
        #pragma unroll
        for (int nt = 0; nt < 8; ++nt) {
            int c = nt*16 + col;
            #pragma unroll
            for (int r = 0; r < 4; ++r) {
                int row = orow0 + r;
                if (row < NN) H[(size_t)row*HD + c] = (_Float16)acc[nt][r];
            }
        }

        float pS[4] = {0.f,0.f,0.f,0.f}, pD[4] = {0.f,0.f,0.f,0.f};
        #pragma unroll
        for (int nt = 0; nt < 8; ++nt) {
            float as_ = asl[nt*16 + col], ad_ = adl[nt*16 + col];
            #pragma unroll
            for (int r = 0; r < 4; ++r) { pS[r] += acc[nt][r]*as_; pD[r] += acc[nt][r]*ad_; }
        }
        #pragma unroll
        for (int off = 1; off < 16; off <<= 1) {
            #pragma unroll
            for (int r = 0; r < 4; ++r) {
                pS[r] += __shfl_xor(pS[r], off);
                pD[r] += __shfl_xor(pD[r], off);
            }
        }
        if (col == 0) {
            #pragma unroll
            for (int r = 0; r < 4; ++r) {
                int row = orow0 + r;
                if (row < NN) { s_src[row] = pS[r]; s_dst[row] = pD[r]; }
            }
        }
    } else if (ei) {
        // ---------------- partition body ----------------
        int* hist = (int*)smem;
        int* base = hist + NBUK;
        for (int i = t; i < NBUK; i += 256) hist[i] = 0;
        __syncthreads();
        int pb = bid - GEMMB;
        int e0 = pb * EPB;
        int e1 = min(e0 + EPB, EE);
        for (int e = e0 + t; e < e1; e += 256) {
            int d = (e < NE) ? ei[NE + e] : e - NE;
            atomicAdd(&hist[d >> BSH], 1);
        }
        __syncthreads();
        for (int i = t; i < NBUK; i += 256) {
            base[i] = atomicAdd(&bucketCount[i], hist[i]);
            hist[i] = 0;                       // reuse as cursor
        }
        __syncthreads();
        for (int e = e0 + t; e < e1; e += 256) {
            int s, d;
            if (e < NE) { s = ei[e]; d = ei[NE + e]; } else { s = e - NE; d = s; }
            int b = d >> BSH;
            int pos = base[b] + atomicAdd(&hist[b], 1);
            if (pos < CAP)
                stage[(size_t)b * CAP + pos] = (unsigned)s | ((unsigned)(d & 255) << 20);
        }
    }
}

// ================= bucket build: inline prefix + deg/scan/scatter =================
__launch_bounds__(256) __global__
void bucket_build_kernel(const unsigned* __restrict__ stage, const int* __restrict__ bucketCount,
                         int* __restrict__ row_ptr, int* __restrict__ csr_src) {
    int b = blockIdx.x;
    int t = threadIdx.x;
    __shared__ int ldeg[256];
    __shared__ int loff[256];
    __shared__ int sbase;
    // inline exclusive prefix of bucketCount[0..b)
    int c = 0;
    if (t < b) c = bucketCount[t];
    if (t + 256 < b) c += bucketCount[t + 256];
    loff[t] = c;
    ldeg[t] = 0;
    __syncthreads();
    for (int off = 128; off >= 1; off >>= 1) {
        if (t < off) loff[t] += loff[t + off];
        __syncthreads();
    }
    if (t == 0) sbase = loff[0];
    __syncthreads();
    int cnt  = bucketCount[b];
    int base = sbase;
    const unsigned* sp = stage + (size_t)b * CAP;
    for (int i = t; i < cnt; i += 256) atomicAdd(&ldeg[sp[i] >> 20], 1);
    __syncthreads();
    int v = ldeg[t];
    loff[t] = v;
    __syncthreads();
    for (int off = 1; off < 256; off <<= 1) {
        int tmp = (t >= off) ? loff[t - off] : 0;
        __syncthreads();
        loff[t] += tmp;
        __syncthreads();
    }
    int excl = loff[t] - v;
    int n = (b << BSH) + t;
    if (n < NN) row_ptr[n] = base + excl;
    if (b == NBUK - 1 && t == 0) row_ptr[NN] = EE;
    ldeg[t] = excl;                        // reuse as cursor
    __syncthreads();
    for (int i = t; i < cnt; i += 256) {
        unsigned p = sp[i];
        int lp = atomicAdd(&ldeg[p >> 20], 1);
        csr_src[base + lp] = (int)(p & 0xFFFFFu);
    }
}

// ================= fused per-node softmax + gather-aggregate (R7-proven body) =================
// 4 nodes/wave (natural order); 4 edges/batch, all 8 gathers issued before compute.
template<int LAYER>
__launch_bounds__(256) __global__
void gat_node_kernel(const int* __restrict__ row_ptr, const int* __restrict__ csr_src,
                     const float* __restrict__ s_src, const float* __restrict__ s_dst,
                     const _Float16* __restrict__ Hh, const float* __restrict__ bias,
                     float* __restrict__ out) {
    int wid = (blockIdx.x * blockDim.x + threadIdx.x) >> 6;
    int lane = threadIdx.x & 63;
    int g = lane >> 4, l16 = lane & 15;
    int n = wid*4 + g;                     // NN divisible by 4: no partial waves
    if (n >= NN) return;
    int r0 = row_ptr[n], r1 = row_ptr[n+1];
    int last = r1 - 1;
    float sdv = s_dst[n];

    float denom = 0.f;
    float acc[8] = {0.f,0.f,0.f,0.f,0.f,0.f,0.f,0.f};

    for (int j = r0; j < r1; j += 4) {
        int jB = j+1 <= last ? j+1 : last;
        int jC = j+2 <= last ? j+2 : last;
        int jD = j+3 <= last ? j+3 : last;
        int sA = csr_src[j];
        int sB = csr_src[jB];
        int sC = csr_src[jC];
        int sD = csr_src[jD];
        // issue all 8 gathers before dependent compute
        f16x8 hA = *(const f16x8*)(Hh + (unsigned)(sA << 7) + l16*8);
        f16x8 hB = *(const f16x8*)(Hh + (unsigned)(sB << 7) + l16*8);
        f16x8 hC = *(const f16x8*)(Hh + (unsigned)(sC << 7) + l16*8);
        f16x8 hD = *(const f16x8*)(Hh + (unsigned)(sD << 7) + l16*8);
        float eA = s_src[sA] + sdv;
        float eB = s_src[sB] + sdv;
        float eC = s_src[sC] + sdv;
        float eD = s_src[sD] + sdv;
        eA = eA > 0.f ? eA : 0.2f*eA;  eB = eB > 0.f ? eB : 0.2f*eB;
        eC = eC > 0.f ? eC : 0.2f*eC;  eD = eD > 0.f ? eD : 0.2f*eD;
        float wA = __expf(fminf(eA, 80.f));
        float wB = (j+1 < r1) ? __expf(fminf(eB, 80.f)) : 0.f;
        float wC = (j+2 < r1) ? __expf(fminf(eC, 80.f)) : 0.f;
        float wD = (j+3 < r1) ? __expf(fminf(eD, 80.f)) : 0.f;
        denom += (wA + wB) + (wC + wD);
        #pragma unroll
        for (int i = 0; i < 8; ++i)
            acc[i] += wA*(float)hA[i] + wB*(float)hB[i] + wC*(float)hC[i] + wD*(float)hD[i];
    }

    float inv = __builtin_amdgcn_rcpf(denom);
    float* op = out + (unsigned)(n << 7) + l16*8;
    float4 b0 = *(const float4*)(bias + l16*8);
    float4 b1 = *(const float4*)(bias + l16*8 + 4);
    float r[8];
    r[0]=acc[0]*inv+b0.x; r[1]=acc[1]*inv+b0.y; r[2]=acc[2]*inv+b0.z; r[3]=acc[3]*inv+b0.w;
    r[4]=acc[4]*inv+b1.x; r[5]=acc[5]*inv+b1.y; r[6]=acc[6]*inv+b1.z; r[7]=acc[7]*inv+b1.w;
    if (LAYER == 1) {
        #pragma unroll
        for (int i = 0; i < 8; ++i) r[i] = fast_tanh(r[i]);
    } else {
        float4 x0 = *(const float4*)op;
        float4 x1 = *(const float4*)(op + 4);
        r[0]=fmaxf(x0.x,r[0]); r[1]=fmaxf(x0.y,r[1]); r[2]=fmaxf(x0.z,r[2]); r[3]=fmaxf(x0.w,r[3]);
        r[4]=fmaxf(x1.x,r[4]); r[5]=fmaxf(x1.y,r[5]); r[6]=fmaxf(x1.z,r[6]); r[7]=fmaxf(x1.w,r[7]);
    }
    *(float4*)op       = make_float4(r[0],r[1],r[2],r[3]);
    *(float4*)(op + 4) = make_float4(r[4],r[5],r[6],r[7]);
}

extern "C" void kernel_launch(void* const* d_in, const int* in_sizes, int n_in,
                              void* d_out, int out_size, void* d_ws, size_t ws_size,
                              hipStream_t stream) {
    const float* x   = (const float*)d_in[0];
    const int*   ei  = (const int*)d_in[1];
    // d_in[2] = edge_weight, unused by GATConv(edge_dim=None)
    const float* W1  = (const float*)d_in[3];
    const float* as1 = (const float*)d_in[4];
    const float* ad1 = (const float*)d_in[5];
    const float* b1  = (const float*)d_in[6];
    const float* W2  = (const float*)d_in[7];
    const float* as2 = (const float*)d_in[8];
    const float* ad2 = (const float*)d_in[9];
    const float* b2  = (const float*)d_in[10];
    float* out = (float*)d_out;

    char* wsb = (char*)d_ws;
    _Float16* h   = (_Float16*)wsb;                  // NH halves (25.6 MB)
    _Float16* Wt1 = h + NH;                          // 16384 halves
    _Float16* Wt2 = Wt1 + HD*HD;                     // 16384 halves
    float* ssrc   = (float*)(Wt2 + HD*HD);           // NN
    float* sdst   = ssrc + NN;                       // NN
    int* row_ptr  = (int*)(sdst + NN);               // NN+2
    int* csr_src  = row_ptr + NN + 2;                // EE
    int* bucketCount = csr_src + EE;                 // NBUK (zeroed by prep each launch)
    unsigned* stage  = (unsigned*)(bucketCount + NBUK + 1);  // NBUK*CAP (9.6 MB)

    dim3 B(256);
    int node_blocks = NN / 16;                       // 6250 (4 nodes/wave, 4 waves/block)

    // ===== prep: Wt transposes (both layers) + zero bucket counters =====
    prep_kernel<<<129, B, 0, stream>>>(W1, W2, Wt1, Wt2, bucketCount);

    // ===== layer-1 GEMM ∥ CSR partition (independent work, one dispatch) =====
    gemm_part_kernel<<<GEMMB + P1B, B, 0, stream>>>(x, Wt1, h, as1, ad1, ssrc, sdst,
                                                    ei, bucketCount, stage);
    bucket_build_kernel<<<NBUK, B, 0, stream>>>(stage, bucketCount, row_ptr, csr_src);

    // ===== layer 1 aggregate =====
    gat_node_kernel<1><<<node_blocks, B, 0, stream>>>(row_ptr, csr_src, ssrc, sdst, h, b1, out);

    // ===== layer 2 (x1 fp32 lives in d_out; max fused into epilogue) =====
    gemm_part_kernel<<<GEMMB, B, 0, stream>>>(out, Wt2, h, as2, ad2, ssrc, sdst,
                                              nullptr, nullptr, nullptr);
    gat_node_kernel<2><<<node_blocks, B, 0, stream>>>(row_ptr, csr_src, ssrc, sdst, h, b2, out);
}